// Round 14
// baseline (176.444 us; speedup 1.0000x reference)
//
#include <hip/hip_runtime.h>

typedef __attribute__((ext_vector_type(8))) short short8;
typedef __attribute__((ext_vector_type(4))) float f32x4;
typedef __attribute__((ext_vector_type(16))) float f32x16;
typedef __attribute__((ext_vector_type(4))) unsigned short us4;

#define DEV __device__ __forceinline__

#define GLD16(gp, lp) __builtin_amdgcn_global_load_lds( \
    (const __attribute__((address_space(1))) void*)(gp), \
    (__attribute__((address_space(3))) void*)(lp), 16, 0, 0)

DEV unsigned short f2bf(float f) {
    union { float f; unsigned u; } v; v.f = f;
    unsigned r = v.u + 0x7fffu + ((v.u >> 16) & 1u);
    return (unsigned short)(r >> 16);
}

DEV float bf2f(unsigned short u) {
    union { unsigned u; float f; } v; v.u = (unsigned)u << 16;
    return v.f;
}

DEV unsigned short f2h(float f) {
    union { _Float16 h; unsigned short u; } v; v.h = (_Float16)f; return v.u;
}

DEV float h2f(unsigned short u) {
    union { _Float16 h; unsigned short u; } v; v.u = u; return (float)v.h;
}

DEV unsigned cvtpk(float lo, float hi) {
    unsigned r;
    asm("v_cvt_pk_bf16_f32 %0, %1, %2" : "=v"(r) : "v"(lo), "v"(hi));
    return r;
}

DEV float fexp2(float x) {
#if __has_builtin(__builtin_amdgcn_exp2f)
    return __builtin_amdgcn_exp2f(x);
#else
    return __expf(x * 0.69314718056f);
#endif
}

// ---------------- prep: x->bf16 convert (blocks 0..4095) + W transpose (blocks 4096..8191) ----------------
__global__ __launch_bounds__(256) void k_prep(const float* __restrict__ x, unsigned short* __restrict__ xb,
                                              const float* __restrict__ wq, const float* __restrict__ wk,
                                              const float* __restrict__ wv, const float* __restrict__ wo,
                                              unsigned short* __restrict__ wt) {
    __shared__ float tile[32][33];
    const int id = blockIdx.x, tid = threadIdx.x;
    if (id < 4096) {
        int i = id * 256 + tid;
        float4 v = ((const float4*)x)[i];
        us4 o = { f2bf(v.x), f2bf(v.y), f2bf(v.z), f2bf(v.w) };
        ((us4*)xb)[i] = o;
        return;
    }
    const int t = (id - 4096) & 1023, z = (id - 4096) >> 10;
    const float* src = (z == 0) ? wq : (z == 1) ? wk : (z == 2) ? wv : wo;
    unsigned short* dst = wt + (size_t)z * (1u << 20);
    const int n0 = (t & 31) * 32, k0 = (t >> 5) * 32;
    const int tx = tid & 31, ty = tid >> 5;
#pragma unroll
    for (int i = 0; i < 4; ++i)
        tile[ty + i * 8][tx] = src[(size_t)(k0 + ty + i * 8) * 1024 + n0 + tx];
    __syncthreads();
#pragma unroll
    for (int i = 0; i < 4; ++i)
        dst[(size_t)(n0 + ty + i * 8) * 1024 + k0 + tx] = f2bf(tile[tx][ty + i * 8]);
}

// ---------------- fused QKV GEMM (bf16 A, reg-staged, XCD-swizzled grid) ----------------
__global__ __launch_bounds__(256) void k_gemm_qkv(const unsigned short* __restrict__ A,
                                                  const unsigned short* __restrict__ Wt,
                                                  const float* __restrict__ bq,
                                                  const float* __restrict__ bk,
                                                  const float* __restrict__ bv,
                                                  const int* __restrict__ mask,
                                                  unsigned short* __restrict__ Qo,
                                                  unsigned short* __restrict__ Ko,
                                                  unsigned short* __restrict__ Vo,
                                                  float qscale) {
    __shared__ unsigned short lA[2][128 * 32];
    __shared__ unsigned short lB[2][3][64 * 32];
    const int id = blockIdx.x;
    const int m0 = ((id & 7) * 4 + ((id >> 3) & 3)) * 128;
    const int n0 = (id >> 5) * 64;
    const int tid = threadIdx.x;
    const int lane = tid & 63;
    const int w = tid >> 6, wm = w >> 1, wn = w & 1;

    const int arow0 = tid >> 2, acl = tid & 3;
    const int arow1 = (tid + 256) >> 2;
    const int brow = tid >> 2;
    const unsigned short* agp0 = A + (size_t)(m0 + arow0) * 1024 + acl * 8;
    const unsigned short* agp1 = A + (size_t)(m0 + arow1) * 1024 + acl * 8;
    const unsigned short* bgp[3];
#pragma unroll
    for (int z = 0; z < 3; ++z)
        bgp[z] = Wt + ((size_t)z << 20) + (size_t)(n0 + brow) * 1024 + acl * 8;
    const int apc0 = ((arow0 << 2) | (acl ^ ((arow0 >> 1) & 3))) * 8;
    const int apc1 = ((arow1 << 2) | (acl ^ ((arow1 >> 1) & 3))) * 8;
    const int bpc  = ((brow  << 2) | (acl ^ ((brow  >> 1) & 3))) * 8;

    int ach[4], bch[2];
#pragma unroll
    for (int mt = 0; mt < 4; ++mt) {
        int row = wm * 64 + mt * 16 + (lane & 15);
        ach[mt] = ((row << 2) | ((lane >> 4) ^ ((row >> 1) & 3))) * 8;
    }
#pragma unroll
    for (int nt = 0; nt < 2; ++nt) {
        int row = wn * 32 + nt * 16 + (lane & 15);
        bch[nt] = ((row << 2) | ((lane >> 4) ^ ((row >> 1) & 3))) * 8;
    }

    f32x4 acc[3][4][2] = {};
    short8 ra0 = *(const short8*)agp0;
    short8 ra1 = *(const short8*)agp1;
    short8 rb[3];
#pragma unroll
    for (int z = 0; z < 3; ++z) rb[z] = *(const short8*)bgp[z];

    for (int t = 0; t < 32; ++t) {
        unsigned short* sA = lA[t & 1];
        *(short8*)(sA + apc0) = ra0;
        *(short8*)(sA + apc1) = ra1;
#pragma unroll
        for (int z = 0; z < 3; ++z)
            *(short8*)(lB[t & 1][z] + bpc) = rb[z];
        if (t < 31) {
            ra0 = *(const short8*)(agp0 + (t + 1) * 32);
            ra1 = *(const short8*)(agp1 + (t + 1) * 32);
#pragma unroll
            for (int z = 0; z < 3; ++z) rb[z] = *(const short8*)(bgp[z] + (t + 1) * 32);
        }
        __syncthreads();
        short8 af[4], bf[3][2];
#pragma unroll
        for (int mt = 0; mt < 4; ++mt) af[mt] = *(const short8*)(sA + ach[mt]);
#pragma unroll
        for (int z = 0; z < 3; ++z)
#pragma unroll
            for (int nt = 0; nt < 2; ++nt) bf[z][nt] = *(const short8*)(lB[t & 1][z] + bch[nt]);
#pragma unroll
        for (int z = 0; z < 3; ++z)
#pragma unroll
            for (int mt = 0; mt < 4; ++mt)
#pragma unroll
                for (int nt = 0; nt < 2; ++nt)
                    acc[z][mt][nt] = __builtin_amdgcn_mfma_f32_16x16x32_bf16(af[mt], bf[z][nt], acc[z][mt][nt], 0, 0, 0);
    }

#pragma unroll
    for (int z = 0; z < 3; ++z) {
        const float* bias = (z == 0) ? bq : (z == 1) ? bk : bv;
        const float scl = (z == 0) ? qscale : 1.0f;
        unsigned short* outp = (z == 0) ? Qo : (z == 1) ? Ko : Vo;
#pragma unroll
        for (int nt = 0; nt < 2; ++nt) {
            const int col = n0 + wn * 32 + nt * 16 + (lane & 15);
            const float bvv = bias[col];
            const int h = col >> 6, hd = col & 63;
#pragma unroll
            for (int mt = 0; mt < 4; ++mt) {
#pragma unroll
                for (int r = 0; r < 4; ++r) {
                    const int row = m0 + wm * 64 + mt * 16 + (lane >> 4) * 4 + r;
                    const int b = row >> 11, s = row & 2047;
                    float v = (acc[z][mt][nt][r] + bvv) * scl;
                    if (z == 2) {
                        v *= (mask[(size_t)b * 2048 + s] ? 1.0f : 0.0f);   // zero masked V rows
                        outp[(size_t)((b * 16 + h) * 64 + hd) * 2048 + s] = f2bf(v);
                    } else {
                        outp[(size_t)((b * 16 + h) * 2048 + s) * 64 + hd] = f2bf(v);
                    }
                }
            }
        }
    }
}

// ---------------- o-proj GEMM: 128x128 tile, 16 MFMA/step/wave, reg-staged, XCD-swizzled ----------------
__global__ __launch_bounds__(256) void k_gemm_o(const unsigned short* __restrict__ A,
                                                const unsigned short* __restrict__ Wt,
                                                const float* __restrict__ bias,
                                                unsigned short* __restrict__ out) {
    __shared__ unsigned short lA[2][128 * 32];
    __shared__ unsigned short lB[2][128 * 32];
    const int id = blockIdx.x;                       // 256 blocks: xcd=id&7, k=id>>3 (0..31)
    const int kk = id >> 3;
    const int m0 = ((id & 7) * 4 + (kk >> 3)) * 128;
    const int n0 = (kk & 7) * 128;
    const int tid = threadIdx.x;
    const int lane = tid & 63;
    const int w = tid >> 6, wm = w >> 1, wn = w & 1;

    const int arow0 = tid >> 2, acl = tid & 3;
    const int arow1 = arow0 + 64;
    const unsigned short* agp0 = A + (size_t)(m0 + arow0) * 1024 + acl * 8;
    const unsigned short* agp1 = A + (size_t)(m0 + arow1) * 1024 + acl * 8;
    const unsigned short* bgp0 = Wt + (size_t)(n0 + arow0) * 1024 + acl * 8;
    const unsigned short* bgp1 = Wt + (size_t)(n0 + arow1) * 1024 + acl * 8;
    const int apc0 = ((arow0 << 2) | (acl ^ ((arow0 >> 1) & 3))) * 8;
    const int apc1 = ((arow1 << 2) | (acl ^ ((arow1 >> 1) & 3))) * 8;

    int ach[4], bch[4];
#pragma unroll
    for (int mt = 0; mt < 4; ++mt) {
        int row = wm * 64 + mt * 16 + (lane & 15);
        ach[mt] = ((row << 2) | ((lane >> 4) ^ ((row >> 1) & 3))) * 8;
    }
#pragma unroll
    for (int nt = 0; nt < 4; ++nt) {
        int row = wn * 64 + nt * 16 + (lane & 15);
        bch[nt] = ((row << 2) | ((lane >> 4) ^ ((row >> 1) & 3))) * 8;
    }

    f32x4 acc[4][4] = {};
    short8 ra0 = *(const short8*)agp0;
    short8 ra1 = *(const short8*)agp1;
    short8 rb0 = *(const short8*)bgp0;
    short8 rb1 = *(const short8*)bgp1;

    for (int t = 0; t < 32; ++t) {
        unsigned short* sA = lA[t & 1];
        unsigned short* sB = lB[t & 1];
        *(short8*)(sA + apc0) = ra0;
        *(short8*)(sA + apc1) = ra1;
        *(short8*)(sB + apc0) = rb0;
        *(short8*)(sB + apc1) = rb1;
        if (t < 31) {
            ra0 = *(const short8*)(agp0 + (t + 1) * 32);
            ra1 = *(const short8*)(agp1 + (t + 1) * 32);
            rb0 = *(const short8*)(bgp0 + (t + 1) * 32);
            rb1 = *(const short8*)(bgp1 + (t + 1) * 32);
        }
        __syncthreads();
        short8 af[4], bf[4];
#pragma unroll
        for (int mt = 0; mt < 4; ++mt) af[mt] = *(const short8*)(sA + ach[mt]);
#pragma unroll
        for (int nt = 0; nt < 4; ++nt) bf[nt] = *(const short8*)(sB + bch[nt]);
#pragma unroll
        for (int mt = 0; mt < 4; ++mt)
#pragma unroll
            for (int nt = 0; nt < 4; ++nt)
                acc[mt][nt] = __builtin_amdgcn_mfma_f32_16x16x32_bf16(af[mt], bf[nt], acc[mt][nt], 0, 0, 0);
    }

#pragma unroll
    for (int nt = 0; nt < 4; ++nt) {
        const int col = n0 + wn * 64 + nt * 16 + (lane & 15);
        const float bv = bias[col];
#pragma unroll
        for (int mt = 0; mt < 4; ++mt)
#pragma unroll
            for (int r = 0; r < 4; ++r) {
                const int row = m0 + wm * 64 + mt * 16 + (lane >> 4) * 4 + r;
                out[(size_t)row * 1024 + col] = f2bf(acc[mt][nt][r] + bv);
            }
    }
}

// ---------------- flash attention: split-KV x4, 64 q-rows/wave, fp16 partials ----------------
// 1024 blocks (32bh x 8qt x 4half), 3 blocks/CU (VGPR ~160 -> 3 waves/SIMD), LDS 33KB.
// Per kt per wave: 8 K + 8 V + 4 m LDS b128 reads serve 64 q-rows (2 fragment groups).
__global__ __launch_bounds__(256, 3) void k_attn(const unsigned short* __restrict__ Qb,
                                                 const unsigned short* __restrict__ Kb,
                                                 const unsigned short* __restrict__ Vt,
                                                 const int* __restrict__ mask,
                                                 unsigned short* __restrict__ po0,
                                                 unsigned short* __restrict__ po1,
                                                 unsigned short* __restrict__ po2,
                                                 unsigned short* __restrict__ po3,
                                                 float* __restrict__ lp) {   // lp[half][bh][s]
    __shared__ unsigned short ksm[2 * 4096];   // 16 KB, 2 buffers
    __shared__ unsigned short vsm[2 * 4096];   // 16 KB
    __shared__ unsigned short mv[512];         // 1 KB: mask as bf16 {0,1} for this quarter
    const int id = blockIdx.x;
    const int xcd = id & 7, slot = id >> 3;                 // 1024 blocks, slot 0..127
    const int half = slot & 3, qt = (slot >> 2) & 7, bh = xcd * 4 + (slot >> 5);
    const int b = bh >> 4, h = bh & 15;
    const int tid = threadIdx.x, l = tid & 63, w = tid >> 6;
    const int q = l & 31, hi = l >> 5;

    {
        int2 m = ((const int2*)(mask + b * 2048 + half * 512))[tid];
        ((unsigned*)mv)[tid] = (m.x ? 0x3F80u : 0u) | ((m.y ? 0x3F80u : 0u) << 16);
    }
    asm volatile("s_waitcnt lgkmcnt(0)" ::: "memory");   // publish mv before first raw barrier

    const size_t bhS = (size_t)bh * 2048;
    const unsigned short* Kbh = Kb + (bhS + half * 512) * 64;    // [512 key][64 d]
    const unsigned short* Vbh = Vt + (size_t)bh * 64 * 2048;     // [64 d][2048 key]
    const int q0 = qt * 256 + w * 64;                            // wave owns 64 q-rows (2 groups)

    const int srow = l >> 3;
    const int sxor = 8 * ((l & 7) ^ ((l >> 3) & 7));
    const unsigned short* Ksrc = Kbh + (size_t)(w * 16 + srow) * 64 + sxor;
    const unsigned short* Vsrc = Vbh + (size_t)(w * 16 + srow) * 2048 + half * 512 + sxor;
    unsigned short* lk0 = ksm + w * 1024;
    unsigned short* lv0 = vsm + w * 1024;

#define STAGE(kt_, buf_) { \
    const unsigned short* gk = Ksrc + (size_t)(kt_) * 4096; \
    const unsigned short* gv = Vsrc + (kt_) * 64; \
    unsigned short* lk = lk0 + (buf_) * 4096; \
    unsigned short* lv = lv0 + (buf_) * 4096; \
    GLD16(gk, lk); GLD16(gk + 512, lk + 512); \
    GLD16(gv, lv); GLD16(gv + 16384, lv + 512); }

    int kro[2][4], vro[2][2][2];
#pragma unroll
    for (int sub = 0; sub < 2; ++sub) {
#pragma unroll
        for (int db = 0; db < 4; ++db) {
            int key = q + sub * 32;
            kro[sub][db] = key * 128 + ((db * 32 + hi * 16) ^ ((key & 7) << 4));
        }
#pragma unroll
        for (int kg = 0; kg < 2; ++kg)
#pragma unroll
            for (int dh = 0; dh < 2; ++dh) {
                int row = q + dh * 32;
                vro[sub][kg][dh] = row * 128 + ((sub * 64 + kg * 32 + hi * 16) ^ ((row & 7) << 4));
            }
    }

    short8 qfA[4], qfB[4];
#pragma unroll
    for (int db = 0; db < 4; ++db) {
        qfA[db] = *(const short8*)(Qb + (bhS + q0 + q) * 64 + db * 16 + hi * 8);
        qfB[db] = *(const short8*)(Qb + (bhS + q0 + 32 + q) * 64 + db * 16 + hi * 8);
    }

    f32x16 o00 = {}, o01 = {}, o10 = {}, o11 = {}, ol0 = {}, ol1 = {};

    STAGE(0, 0);

    for (int kt = 0; kt < 8; ++kt) {
        const int cur = kt & 1;
        if (kt < 7) {
            STAGE(kt + 1, cur ^ 1);
            asm volatile("s_waitcnt vmcnt(4)" ::: "memory");
        } else {
            asm volatile("s_waitcnt vmcnt(0)" ::: "memory");
        }
        __builtin_amdgcn_s_barrier();
        __builtin_amdgcn_sched_barrier(0);
        const char* kb = (const char*)(ksm + cur * 4096);
        const char* vb = (const char*)(vsm + cur * 4096);
#pragma unroll
        for (int sub = 0; sub < 2; ++sub) {
            short8 kf0 = *(const short8*)(kb + kro[sub][0]);
            short8 kf1 = *(const short8*)(kb + kro[sub][1]);
            short8 kf2 = *(const short8*)(kb + kro[sub][2]);
            short8 kf3 = *(const short8*)(kb + kro[sub][3]);
            f32x16 sa0 = {}, sa1 = {};
            __builtin_amdgcn_s_setprio(1);
            sa0 = __builtin_amdgcn_mfma_f32_32x32x16_bf16(kf0, qfA[0], sa0, 0, 0, 0);
            sa1 = __builtin_amdgcn_mfma_f32_32x32x16_bf16(kf0, qfB[0], sa1, 0, 0, 0);
            sa0 = __builtin_amdgcn_mfma_f32_32x32x16_bf16(kf1, qfA[1], sa0, 0, 0, 0);
            sa1 = __builtin_amdgcn_mfma_f32_32x32x16_bf16(kf1, qfB[1], sa1, 0, 0, 0);
            sa0 = __builtin_amdgcn_mfma_f32_32x32x16_bf16(kf2, qfA[2], sa0, 0, 0, 0);
            sa1 = __builtin_amdgcn_mfma_f32_32x32x16_bf16(kf2, qfB[2], sa1, 0, 0, 0);
            sa0 = __builtin_amdgcn_mfma_f32_32x32x16_bf16(kf3, qfA[3], sa0, 0, 0, 0);
            sa1 = __builtin_amdgcn_mfma_f32_32x32x16_bf16(kf3, qfB[3], sa1, 0, 0, 0);
            __builtin_amdgcn_s_setprio(0);
            union { unsigned u[4]; short8 s8; } afA[2], afB[2];
            {
                float p[16];
#pragma unroll
                for (int r = 0; r < 16; ++r) p[r] = fexp2(sa0[r]);
#pragma unroll
                for (int kg = 0; kg < 2; ++kg) {
                    unsigned P0 = cvtpk(p[kg * 8 + 0], p[kg * 8 + 1]);
                    unsigned P1 = cvtpk(p[kg * 8 + 2], p[kg * 8 + 3]);
                    unsigned P2 = cvtpk(p[kg * 8 + 4], p[kg * 8 + 5]);
                    unsigned P3 = cvtpk(p[kg * 8 + 6], p[kg * 8 + 7]);
                    asm("v_permlane32_swap_b32 %0, %1" : "+v"(P0), "+v"(P2));
                    asm("v_permlane32_swap_b32 %0, %1" : "+v"(P1), "+v"(P3));
                    afA[kg].u[0] = P0; afA[kg].u[1] = P1; afA[kg].u[2] = P2; afA[kg].u[3] = P3;
                }
            }
            {
                float p[16];
#pragma unroll
                for (int r = 0; r < 16; ++r) p[r] = fexp2(sa1[r]);
#pragma unroll
                for (int kg = 0; kg < 2; ++kg) {
                    unsigned P0 = cvtpk(p[kg * 8 + 0], p[kg * 8 + 1]);
                    unsigned P1 = cvtpk(p[kg * 8 + 2], p[kg * 8 + 3]);
                    unsigned P2 = cvtpk(p[kg * 8 + 4], p[kg * 8 + 5]);
                    unsigned P3 = cvtpk(p[kg * 8 + 6], p[kg * 8 + 7]);
                    asm("v_permlane32_swap_b32 %0, %1" : "+v"(P0), "+v"(P2));
                    asm("v_permlane32_swap_b32 %0, %1" : "+v"(P1), "+v"(P3));
                    afB[kg].u[0] = P0; afB[kg].u[1] = P1; afB[kg].u[2] = P2; afB[kg].u[3] = P3;
                }
            }
#pragma unroll
            for (int kg = 0; kg < 2; ++kg) {
                short8 vf0 = *(const short8*)(vb + vro[sub][kg][0]);
                short8 vf1 = *(const short8*)(vb + vro[sub][kg][1]);
                short8 mfr = *(const short8*)(mv + kt * 64 + sub * 32 + kg * 16 + hi * 8);
                __builtin_amdgcn_s_setprio(1);
                o00 = __builtin_amdgcn_mfma_f32_32x32x16_bf16(afA[kg].s8, vf0, o00, 0, 0, 0);
                o01 = __builtin_amdgcn_mfma_f32_32x32x16_bf16(afA[kg].s8, vf1, o01, 0, 0, 0);
                o10 = __builtin_amdgcn_mfma_f32_32x32x16_bf16(afB[kg].s8, vf0, o10, 0, 0, 0);
                o11 = __builtin_amdgcn_mfma_f32_32x32x16_bf16(afB[kg].s8, vf1, o11, 0, 0, 0);
                ol0 = __builtin_amdgcn_mfma_f32_32x32x16_bf16(afA[kg].s8, mfr, ol0, 0, 0, 0);
                ol1 = __builtin_amdgcn_mfma_f32_32x32x16_bf16(afB[kg].s8, mfr, ol1, 0, 0, 0);
                __builtin_amdgcn_s_setprio(0);
            }
        }
        __builtin_amdgcn_sched_barrier(0);
        if (kt < 7) __builtin_amdgcn_s_barrier();
    }
#undef STAGE

    float* lpx = lp + (size_t)half * 65536 + bhS;
    if (q == 0) {
#pragma unroll
        for (int r = 0; r < 16; ++r) {
            int crow = (r & 3) + 8 * (r >> 2) + 4 * hi;
            lpx[q0 + crow] = ol0[r];
            lpx[q0 + 32 + crow] = ol1[r];
        }
    }
    unsigned short* pox = (half == 0) ? po0 : (half == 1) ? po1 : (half == 2) ? po2 : po3;
    unsigned short* popA = pox + ((size_t)b * 2048 + q0) * 1024 + h * 64 + q;
    unsigned short* popB = popA + (size_t)32 * 1024;
#pragma unroll
    for (int r = 0; r < 16; ++r) {
        int qrow = (r & 3) + 8 * (r >> 2) + 4 * hi;
        popA[(size_t)qrow * 1024] = f2h(o00[r]);        // fp16 partials (2^-11 noise)
        popA[(size_t)qrow * 1024 + 32] = f2h(o01[r]);
        popB[(size_t)qrow * 1024] = f2h(o10[r]);
        popB[(size_t)qrow * 1024 + 32] = f2h(o11[r]);
    }
}

// ---------------- combine split-KV x4 fp16 partials: ao = sum(po)/sum(l), bf16 out ----------------
__global__ __launch_bounds__(256) void k_comb(const unsigned short* __restrict__ po0,
                                              const unsigned short* __restrict__ po1,
                                              const unsigned short* __restrict__ po2,
                                              const unsigned short* __restrict__ po3,
                                              const float* __restrict__ lp,
                                              unsigned short* __restrict__ ao) {
    const int idx8 = blockIdx.x * 256 + threadIdx.x;   // 8 elems per thread
    const int e = idx8 * 8;
    const int row = e >> 10, c = e & 1023;
    const int h = c >> 6, b = row >> 11, s = row & 2047;
    const size_t li = ((size_t)(b * 16 + h) << 11) + s;
    const float lsum = lp[li] + lp[65536 + li] + lp[2 * 65536 + li] + lp[3 * 65536 + li];
    const float rinv = __builtin_amdgcn_rcpf(lsum);
    short8 a0 = ((const short8*)po0)[idx8];
    short8 a1 = ((const short8*)po1)[idx8];
    short8 a2 = ((const short8*)po2)[idx8];
    short8 a3 = ((const short8*)po3)[idx8];
    short8 o;
#pragma unroll
    for (int j = 0; j < 8; ++j) {
        float s4 = (h2f((unsigned short)a0[j]) + h2f((unsigned short)a1[j]))
                 + (h2f((unsigned short)a2[j]) + h2f((unsigned short)a3[j]));
        o[j] = (short)f2bf(s4 * rinv);
    }
    ((short8*)ao)[idx8] = o;
}

// ---------------- residual + LayerNorm: out = LN(x + oproj) ----------------
__global__ __launch_bounds__(256) void k_ln(const float* __restrict__ x, const unsigned short* __restrict__ op,
                                            const float* __restrict__ g, const float* __restrict__ be,
                                            float* __restrict__ out) {
    const int row = blockIdx.x, tid = threadIdx.x;
    const float4 xv = ((const float4*)(x + (size_t)row * 1024))[tid];
    const us4 ov = ((const us4*)(op + (size_t)row * 1024))[tid];
    float4 v = { xv.x + bf2f(ov.x), xv.y + bf2f(ov.y), xv.z + bf2f(ov.z), xv.w + bf2f(ov.w) };
    float sum = v.x + v.y + v.z + v.w;
    float ss = v.x * v.x + v.y * v.y + v.z * v.z + v.w * v.w;
#pragma unroll
    for (int xm = 1; xm < 64; xm <<= 1) {
        sum += __shfl_xor(sum, xm, 64);
        ss += __shfl_xor(ss, xm, 64);
    }
    __shared__ float red[8];
    const int lane = tid & 63, w = tid >> 6;
    if (lane == 0) { red[w] = sum; red[4 + w] = ss; }
    __syncthreads();
    sum = red[0] + red[1] + red[2] + red[3];
    ss = red[4] + red[5] + red[6] + red[7];
    const float mu = sum * (1.0f / 1024.0f);
    const float rstd = rsqrtf(ss * (1.0f / 1024.0f) - mu * mu + 1e-5f);
    const float4 gv = ((const float4*)g)[tid];
    const float4 bv = ((const float4*)be)[tid];
    float4 o = { (v.x - mu) * rstd * gv.x + bv.x, (v.y - mu) * rstd * gv.y + bv.y,
                 (v.z - mu) * rstd * gv.z + bv.z, (v.w - mu) * rstd * gv.w + bv.w };
    ((float4*)(out + (size_t)row * 1024))[tid] = o;
}

extern "C" void kernel_launch(void* const* d_in, const int* in_sizes, int n_in,
                              void* d_out, int out_size, void* d_ws, size_t ws_size,
                              hipStream_t stream) {
    const float* x        = (const float*)d_in[0];
    const int*   mask     = (const int*)d_in[1];
    const float* wq       = (const float*)d_in[2];
    const float* bq       = (const float*)d_in[3];
    const float* wk       = (const float*)d_in[4];
    const float* bk       = (const float*)d_in[5];
    const float* wv       = (const float*)d_in[6];
    const float* bv       = (const float*)d_in[7];
    const float* wo       = (const float*)d_in[8];
    const float* bo       = (const float*)d_in[9];
    const float* ln_g     = (const float*)d_in[11];
    const float* ln_b     = (const float*)d_in[12];

    char* ws = (char*)d_ws;
    unsigned short* xb  = (unsigned short*)(ws);                    // 0-8 MB   x bf16; reused as po0
    unsigned short* wt  = (unsigned short*)(ws + (8ll  << 20));     // 8-16 MB  4x Wt bf16
    unsigned short* qb  = (unsigned short*)(ws + (16ll << 20));     // 16-24 MB Q; reused as ao
    unsigned short* kb  = (unsigned short*)(ws + (24ll << 20));     // 24-32 MB K; reused as opj
    unsigned short* vtb = (unsigned short*)(ws + (32ll << 20));     // 32-40 MB V^T (mask-zeroed)
    unsigned short* po1 = (unsigned short*)(ws + (40ll << 20));     // 40-48 MB partial O half1 (fp16)
    float*          lp  = (float*)(ws + (48ll << 20));              // 1 MB: l partials [4][32][2048]
    unsigned short* po0 = xb;                                       // fp16
    unsigned short* po2 = (unsigned short*)d_out;                   // d_out as scratch (16 MB):
    unsigned short* po3 = po2 + (4ll << 20);                        // po2 + po3 fp16; k_ln overwrites later
    unsigned short* ao  = qb;
    unsigned short* opj = kb;

    const float qscale = 0.125f * 1.44269504f;   // 1/sqrt(Hd) * log2(e), folded into Q
    // attn_bias (1,H,1,1) is constant across keys => softmax shift-invariant => dropped.

    k_prep<<<8192, 256, 0, stream>>>(x, xb, wq, wk, wv, wo, wt);
    k_gemm_qkv<<<512, 256, 0, stream>>>(xb, wt, bq, bk, bv, mask, qb, kb, vtb, qscale);
    k_attn<<<1024, 256, 0, stream>>>(qb, kb, vtb, mask, po0, po1, po2, po3, lp);
    k_comb<<<2048, 256, 0, stream>>>(po0, po1, po2, po3, lp, ao);
    k_gemm_o<<<256, 256, 0, stream>>>(ao, wt + (3u << 20), bo, opj);
    k_ln<<<4096, 256, 0, stream>>>(x, opj, ln_g, ln_b, (float*)d_out);
}

// Round 15
// 129.307 us; speedup vs baseline: 1.3645x; 1.3645x over previous
//
#include <hip/hip_runtime.h>

typedef __attribute__((ext_vector_type(8))) short short8;
typedef __attribute__((ext_vector_type(4))) float f32x4;
typedef __attribute__((ext_vector_type(16))) float f32x16;
typedef __attribute__((ext_vector_type(4))) unsigned short us4;

#define DEV __device__ __forceinline__

#define GLD16(gp, lp) __builtin_amdgcn_global_load_lds( \
    (const __attribute__((address_space(1))) void*)(gp), \
    (__attribute__((address_space(3))) void*)(lp), 16, 0, 0)

DEV unsigned short f2bf(float f) {
    union { float f; unsigned u; } v; v.f = f;
    unsigned r = v.u + 0x7fffu + ((v.u >> 16) & 1u);
    return (unsigned short)(r >> 16);
}

DEV float bf2f(unsigned short u) {
    union { unsigned u; float f; } v; v.u = (unsigned)u << 16;
    return v.f;
}

DEV unsigned short f2h(float f) {
    union { _Float16 h; unsigned short u; } v; v.h = (_Float16)f; return v.u;
}

DEV float h2f(unsigned short u) {
    union { _Float16 h; unsigned short u; } v; v.u = u; return (float)v.h;
}

DEV unsigned cvtpk(float lo, float hi) {
    unsigned r;
    asm("v_cvt_pk_bf16_f32 %0, %1, %2" : "=v"(r) : "v"(lo), "v"(hi));
    return r;
}

DEV float fexp2(float x) {
#if __has_builtin(__builtin_amdgcn_exp2f)
    return __builtin_amdgcn_exp2f(x);
#else
    return __expf(x * 0.69314718056f);
#endif
}

// ---------------- prep: x->bf16 convert (blocks 0..4095) + W transpose (blocks 4096..8191) ----------------
__global__ __launch_bounds__(256) void k_prep(const float* __restrict__ x, unsigned short* __restrict__ xb,
                                              const float* __restrict__ wq, const float* __restrict__ wk,
                                              const float* __restrict__ wv, const float* __restrict__ wo,
                                              unsigned short* __restrict__ wt) {
    __shared__ float tile[32][33];
    const int id = blockIdx.x, tid = threadIdx.x;
    if (id < 4096) {
        int i = id * 256 + tid;
        float4 v = ((const float4*)x)[i];
        us4 o = { f2bf(v.x), f2bf(v.y), f2bf(v.z), f2bf(v.w) };
        ((us4*)xb)[i] = o;
        return;
    }
    const int t = (id - 4096) & 1023, z = (id - 4096) >> 10;
    const float* src = (z == 0) ? wq : (z == 1) ? wk : (z == 2) ? wv : wo;
    unsigned short* dst = wt + (size_t)z * (1u << 20);
    const int n0 = (t & 31) * 32, k0 = (t >> 5) * 32;
    const int tx = tid & 31, ty = tid >> 5;
#pragma unroll
    for (int i = 0; i < 4; ++i)
        tile[ty + i * 8][tx] = src[(size_t)(k0 + ty + i * 8) * 1024 + n0 + tx];
    __syncthreads();
#pragma unroll
    for (int i = 0; i < 4; ++i)
        dst[(size_t)(n0 + ty + i * 8) * 1024 + k0 + tx] = f2bf(tile[tx][ty + i * 8]);
}

// ---------------- fused QKV GEMM (bf16 A, reg-staged, XCD-swizzled grid) ----------------
__global__ __launch_bounds__(256) void k_gemm_qkv(const unsigned short* __restrict__ A,
                                                  const unsigned short* __restrict__ Wt,
                                                  const float* __restrict__ bq,
                                                  const float* __restrict__ bk,
                                                  const float* __restrict__ bv,
                                                  const int* __restrict__ mask,
                                                  unsigned short* __restrict__ Qo,
                                                  unsigned short* __restrict__ Ko,
                                                  unsigned short* __restrict__ Vo,
                                                  float qscale) {
    __shared__ unsigned short lA[2][128 * 32];
    __shared__ unsigned short lB[2][3][64 * 32];
    const int id = blockIdx.x;
    const int m0 = ((id & 7) * 4 + ((id >> 3) & 3)) * 128;
    const int n0 = (id >> 5) * 64;
    const int tid = threadIdx.x;
    const int lane = tid & 63;
    const int w = tid >> 6, wm = w >> 1, wn = w & 1;

    const int arow0 = tid >> 2, acl = tid & 3;
    const int arow1 = (tid + 256) >> 2;
    const int brow = tid >> 2;
    const unsigned short* agp0 = A + (size_t)(m0 + arow0) * 1024 + acl * 8;
    const unsigned short* agp1 = A + (size_t)(m0 + arow1) * 1024 + acl * 8;
    const unsigned short* bgp[3];
#pragma unroll
    for (int z = 0; z < 3; ++z)
        bgp[z] = Wt + ((size_t)z << 20) + (size_t)(n0 + brow) * 1024 + acl * 8;
    const int apc0 = ((arow0 << 2) | (acl ^ ((arow0 >> 1) & 3))) * 8;
    const int apc1 = ((arow1 << 2) | (acl ^ ((arow1 >> 1) & 3))) * 8;
    const int bpc  = ((brow  << 2) | (acl ^ ((brow  >> 1) & 3))) * 8;

    int ach[4], bch[2];
#pragma unroll
    for (int mt = 0; mt < 4; ++mt) {
        int row = wm * 64 + mt * 16 + (lane & 15);
        ach[mt] = ((row << 2) | ((lane >> 4) ^ ((row >> 1) & 3))) * 8;
    }
#pragma unroll
    for (int nt = 0; nt < 2; ++nt) {
        int row = wn * 32 + nt * 16 + (lane & 15);
        bch[nt] = ((row << 2) | ((lane >> 4) ^ ((row >> 1) & 3))) * 8;
    }

    f32x4 acc[3][4][2] = {};
    short8 ra0 = *(const short8*)agp0;
    short8 ra1 = *(const short8*)agp1;
    short8 rb[3];
#pragma unroll
    for (int z = 0; z < 3; ++z) rb[z] = *(const short8*)bgp[z];

    for (int t = 0; t < 32; ++t) {
        unsigned short* sA = lA[t & 1];
        *(short8*)(sA + apc0) = ra0;
        *(short8*)(sA + apc1) = ra1;
#pragma unroll
        for (int z = 0; z < 3; ++z)
            *(short8*)(lB[t & 1][z] + bpc) = rb[z];
        if (t < 31) {
            ra0 = *(const short8*)(agp0 + (t + 1) * 32);
            ra1 = *(const short8*)(agp1 + (t + 1) * 32);
#pragma unroll
            for (int z = 0; z < 3; ++z) rb[z] = *(const short8*)(bgp[z] + (t + 1) * 32);
        }
        __syncthreads();
        short8 af[4], bf[3][2];
#pragma unroll
        for (int mt = 0; mt < 4; ++mt) af[mt] = *(const short8*)(sA + ach[mt]);
#pragma unroll
        for (int z = 0; z < 3; ++z)
#pragma unroll
            for (int nt = 0; nt < 2; ++nt) bf[z][nt] = *(const short8*)(lB[t & 1][z] + bch[nt]);
#pragma unroll
        for (int z = 0; z < 3; ++z)
#pragma unroll
            for (int mt = 0; mt < 4; ++mt)
#pragma unroll
                for (int nt = 0; nt < 2; ++nt)
                    acc[z][mt][nt] = __builtin_amdgcn_mfma_f32_16x16x32_bf16(af[mt], bf[z][nt], acc[z][mt][nt], 0, 0, 0);
    }

#pragma unroll
    for (int z = 0; z < 3; ++z) {
        const float* bias = (z == 0) ? bq : (z == 1) ? bk : bv;
        const float scl = (z == 0) ? qscale : 1.0f;
        unsigned short* outp = (z == 0) ? Qo : (z == 1) ? Ko : Vo;
#pragma unroll
        for (int nt = 0; nt < 2; ++nt) {
            const int col = n0 + wn * 32 + nt * 16 + (lane & 15);
            const float bvv = bias[col];
            const int h = col >> 6, hd = col & 63;
#pragma unroll
            for (int mt = 0; mt < 4; ++mt) {
#pragma unroll
                for (int r = 0; r < 4; ++r) {
                    const int row = m0 + wm * 64 + mt * 16 + (lane >> 4) * 4 + r;
                    const int b = row >> 11, s = row & 2047;
                    float v = (acc[z][mt][nt][r] + bvv) * scl;
                    if (z == 2) {
                        v *= (mask[(size_t)b * 2048 + s] ? 1.0f : 0.0f);   // zero masked V rows
                        outp[(size_t)((b * 16 + h) * 64 + hd) * 2048 + s] = f2bf(v);
                    } else {
                        outp[(size_t)((b * 16 + h) * 2048 + s) * 64 + hd] = f2bf(v);
                    }
                }
            }
        }
    }
}

// ---------------- o-proj GEMM: 128x128 tile, 16 MFMA/step/wave, reg-staged, XCD-swizzled ----------------
__global__ __launch_bounds__(256) void k_gemm_o(const unsigned short* __restrict__ A,
                                                const unsigned short* __restrict__ Wt,
                                                const float* __restrict__ bias,
                                                unsigned short* __restrict__ out) {
    __shared__ unsigned short lA[2][128 * 32];
    __shared__ unsigned short lB[2][128 * 32];
    const int id = blockIdx.x;                       // 256 blocks: xcd=id&7, k=id>>3 (0..31)
    const int kk = id >> 3;
    const int m0 = ((id & 7) * 4 + (kk >> 3)) * 128;
    const int n0 = (kk & 7) * 128;
    const int tid = threadIdx.x;
    const int lane = tid & 63;
    const int w = tid >> 6, wm = w >> 1, wn = w & 1;

    const int arow0 = tid >> 2, acl = tid & 3;
    const int arow1 = arow0 + 64;
    const unsigned short* agp0 = A + (size_t)(m0 + arow0) * 1024 + acl * 8;
    const unsigned short* agp1 = A + (size_t)(m0 + arow1) * 1024 + acl * 8;
    const unsigned short* bgp0 = Wt + (size_t)(n0 + arow0) * 1024 + acl * 8;
    const unsigned short* bgp1 = Wt + (size_t)(n0 + arow1) * 1024 + acl * 8;
    const int apc0 = ((arow0 << 2) | (acl ^ ((arow0 >> 1) & 3))) * 8;
    const int apc1 = ((arow1 << 2) | (acl ^ ((arow1 >> 1) & 3))) * 8;

    int ach[4], bch[4];
#pragma unroll
    for (int mt = 0; mt < 4; ++mt) {
        int row = wm * 64 + mt * 16 + (lane & 15);
        ach[mt] = ((row << 2) | ((lane >> 4) ^ ((row >> 1) & 3))) * 8;
    }
#pragma unroll
    for (int nt = 0; nt < 4; ++nt) {
        int row = wn * 64 + nt * 16 + (lane & 15);
        bch[nt] = ((row << 2) | ((lane >> 4) ^ ((row >> 1) & 3))) * 8;
    }

    f32x4 acc[4][4] = {};
    short8 ra0 = *(const short8*)agp0;
    short8 ra1 = *(const short8*)agp1;
    short8 rb0 = *(const short8*)bgp0;
    short8 rb1 = *(const short8*)bgp1;

    for (int t = 0; t < 32; ++t) {
        unsigned short* sA = lA[t & 1];
        unsigned short* sB = lB[t & 1];
        *(short8*)(sA + apc0) = ra0;
        *(short8*)(sA + apc1) = ra1;
        *(short8*)(sB + apc0) = rb0;
        *(short8*)(sB + apc1) = rb1;
        if (t < 31) {
            ra0 = *(const short8*)(agp0 + (t + 1) * 32);
            ra1 = *(const short8*)(agp1 + (t + 1) * 32);
            rb0 = *(const short8*)(bgp0 + (t + 1) * 32);
            rb1 = *(const short8*)(bgp1 + (t + 1) * 32);
        }
        __syncthreads();
        short8 af[4], bf[4];
#pragma unroll
        for (int mt = 0; mt < 4; ++mt) af[mt] = *(const short8*)(sA + ach[mt]);
#pragma unroll
        for (int nt = 0; nt < 4; ++nt) bf[nt] = *(const short8*)(sB + bch[nt]);
#pragma unroll
        for (int mt = 0; mt < 4; ++mt)
#pragma unroll
            for (int nt = 0; nt < 4; ++nt)
                acc[mt][nt] = __builtin_amdgcn_mfma_f32_16x16x32_bf16(af[mt], bf[nt], acc[mt][nt], 0, 0, 0);
    }

#pragma unroll
    for (int nt = 0; nt < 4; ++nt) {
        const int col = n0 + wn * 64 + nt * 16 + (lane & 15);
        const float bv = bias[col];
#pragma unroll
        for (int mt = 0; mt < 4; ++mt)
#pragma unroll
            for (int r = 0; r < 4; ++r) {
                const int row = m0 + wm * 64 + mt * 16 + (lane >> 4) * 4 + r;
                out[(size_t)row * 1024 + col] = f2bf(acc[mt][nt][r] + bv);
            }
    }
}

// ---------------- flash attention: split-KV x4, 32 q-rows/wave, fp16 partials (R11-proven) ----------------
// 2048 blocks (32bh x 16qt x 4half), 4 blocks/CU, VGPR 56, occupancy ~31%.
__global__ __launch_bounds__(256, 4) void k_attn(const unsigned short* __restrict__ Qb,
                                                 const unsigned short* __restrict__ Kb,
                                                 const unsigned short* __restrict__ Vt,
                                                 const int* __restrict__ mask,
                                                 unsigned short* __restrict__ po0,
                                                 unsigned short* __restrict__ po1,
                                                 unsigned short* __restrict__ po2,
                                                 unsigned short* __restrict__ po3,
                                                 float* __restrict__ lp) {   // lp[half][bh][s]
    __shared__ unsigned short ksm[2 * 4096];   // 16 KB, 2 buffers
    __shared__ unsigned short vsm[2 * 4096];   // 16 KB
    __shared__ unsigned short mv[512];         // 1 KB: mask as bf16 {0,1} for this quarter
    const int id = blockIdx.x;
    const int xcd = id & 7, slot = id >> 3;                 // 2048 blocks, slot 0..255
    const int half = slot & 3, qt = (slot >> 2) & 15, bh = xcd * 4 + (slot >> 6);
    const int b = bh >> 4, h = bh & 15;
    const int tid = threadIdx.x, l = tid & 63, w = tid >> 6;
    const int q = l & 31, hi = l >> 5;

    {
        int2 m = ((const int2*)(mask + b * 2048 + half * 512))[tid];
        ((unsigned*)mv)[tid] = (m.x ? 0x3F80u : 0u) | ((m.y ? 0x3F80u : 0u) << 16);
    }
    asm volatile("s_waitcnt lgkmcnt(0)" ::: "memory");   // publish mv before first raw barrier

    const size_t bhS = (size_t)bh * 2048;
    const unsigned short* Kbh = Kb + (bhS + half * 512) * 64;    // [512 key][64 d]
    const unsigned short* Vbh = Vt + (size_t)bh * 64 * 2048;     // [64 d][2048 key]
    const int q0 = qt * 128 + w * 32;                            // wave owns 32 q-rows

    const int srow = l >> 3;
    const int sxor = 8 * ((l & 7) ^ ((l >> 3) & 7));
    const unsigned short* Ksrc = Kbh + (size_t)(w * 16 + srow) * 64 + sxor;
    const unsigned short* Vsrc = Vbh + (size_t)(w * 16 + srow) * 2048 + half * 512 + sxor;
    unsigned short* lk0 = ksm + w * 1024;
    unsigned short* lv0 = vsm + w * 1024;

#define STAGE(kt_, buf_) { \
    const unsigned short* gk = Ksrc + (size_t)(kt_) * 4096; \
    const unsigned short* gv = Vsrc + (kt_) * 64; \
    unsigned short* lk = lk0 + (buf_) * 4096; \
    unsigned short* lv = lv0 + (buf_) * 4096; \
    GLD16(gk, lk); GLD16(gk + 512, lk + 512); \
    GLD16(gv, lv); GLD16(gv + 16384, lv + 512); }

    int kro[2][4], vro[2][2][2];
#pragma unroll
    for (int sub = 0; sub < 2; ++sub) {
#pragma unroll
        for (int db = 0; db < 4; ++db) {
            int key = q + sub * 32;
            kro[sub][db] = key * 128 + ((db * 32 + hi * 16) ^ ((key & 7) << 4));
        }
#pragma unroll
        for (int kg = 0; kg < 2; ++kg)
#pragma unroll
            for (int dh = 0; dh < 2; ++dh) {
                int row = q + dh * 32;
                vro[sub][kg][dh] = row * 128 + ((sub * 64 + kg * 32 + hi * 16) ^ ((row & 7) << 4));
            }
    }

    short8 qf[4];
#pragma unroll
    for (int db = 0; db < 4; ++db)
        qf[db] = *(const short8*)(Qb + (bhS + q0 + q) * 64 + db * 16 + hi * 8);

    f32x16 o0 = {}, o1 = {}, ol = {};

    STAGE(0, 0);

    for (int kt = 0; kt < 8; ++kt) {
        const int cur = kt & 1;
        if (kt < 7) {
            STAGE(kt + 1, cur ^ 1);
            asm volatile("s_waitcnt vmcnt(4)" ::: "memory");
        } else {
            asm volatile("s_waitcnt vmcnt(0)" ::: "memory");
        }
        __builtin_amdgcn_s_barrier();
        __builtin_amdgcn_sched_barrier(0);
        const char* kb = (const char*)(ksm + cur * 4096);
        const char* vb = (const char*)(vsm + cur * 4096);
#pragma unroll
        for (int sub = 0; sub < 2; ++sub) {
            short8 kf0 = *(const short8*)(kb + kro[sub][0]);
            short8 kf1 = *(const short8*)(kb + kro[sub][1]);
            short8 kf2 = *(const short8*)(kb + kro[sub][2]);
            short8 kf3 = *(const short8*)(kb + kro[sub][3]);
            f32x16 sa = {};
            __builtin_amdgcn_s_setprio(1);
            sa = __builtin_amdgcn_mfma_f32_32x32x16_bf16(kf0, qf[0], sa, 0, 0, 0);
            sa = __builtin_amdgcn_mfma_f32_32x32x16_bf16(kf1, qf[1], sa, 0, 0, 0);
            sa = __builtin_amdgcn_mfma_f32_32x32x16_bf16(kf2, qf[2], sa, 0, 0, 0);
            sa = __builtin_amdgcn_mfma_f32_32x32x16_bf16(kf3, qf[3], sa, 0, 0, 0);
            __builtin_amdgcn_s_setprio(0);
            float p[16];
#pragma unroll
            for (int r = 0; r < 16; ++r) p[r] = fexp2(sa[r]);
            union { unsigned u[4]; short8 s8; } af[2];
#pragma unroll
            for (int kg = 0; kg < 2; ++kg) {
                unsigned P0 = cvtpk(p[kg * 8 + 0], p[kg * 8 + 1]);
                unsigned P1 = cvtpk(p[kg * 8 + 2], p[kg * 8 + 3]);
                unsigned P2 = cvtpk(p[kg * 8 + 4], p[kg * 8 + 5]);
                unsigned P3 = cvtpk(p[kg * 8 + 6], p[kg * 8 + 7]);
                asm("v_permlane32_swap_b32 %0, %1" : "+v"(P0), "+v"(P2));
                asm("v_permlane32_swap_b32 %0, %1" : "+v"(P1), "+v"(P3));
                af[kg].u[0] = P0; af[kg].u[1] = P1; af[kg].u[2] = P2; af[kg].u[3] = P3;
            }
#pragma unroll
            for (int kg = 0; kg < 2; ++kg) {
                short8 vf0 = *(const short8*)(vb + vro[sub][kg][0]);
                short8 vf1 = *(const short8*)(vb + vro[sub][kg][1]);
                short8 mfr = *(const short8*)(mv + kt * 64 + sub * 32 + kg * 16 + hi * 8);
                __builtin_amdgcn_s_setprio(1);
                o0 = __builtin_amdgcn_mfma_f32_32x32x16_bf16(af[kg].s8, vf0, o0, 0, 0, 0);
                o1 = __builtin_amdgcn_mfma_f32_32x32x16_bf16(af[kg].s8, vf1, o1, 0, 0, 0);
                ol = __builtin_amdgcn_mfma_f32_32x32x16_bf16(af[kg].s8, mfr, ol, 0, 0, 0);
                __builtin_amdgcn_s_setprio(0);
            }
        }
        __builtin_amdgcn_sched_barrier(0);
        if (kt < 7) __builtin_amdgcn_s_barrier();
    }
#undef STAGE

    float* lpx = lp + (size_t)half * 65536 + bhS;
    if (q == 0) {
#pragma unroll
        for (int r = 0; r < 16; ++r) {
            int crow = (r & 3) + 8 * (r >> 2) + 4 * hi;
            lpx[q0 + crow] = ol[r];
        }
    }
    unsigned short* pox = (half == 0) ? po0 : (half == 1) ? po1 : (half == 2) ? po2 : po3;
    unsigned short* pop = pox + ((size_t)b * 2048 + q0) * 1024 + h * 64 + q;
#pragma unroll
    for (int r = 0; r < 16; ++r) {
        int qrow = (r & 3) + 8 * (r >> 2) + 4 * hi;
        pop[(size_t)qrow * 1024] = f2h(o0[r]);          // fp16 partials (2^-11 noise)
        pop[(size_t)qrow * 1024 + 32] = f2h(o1[r]);
    }
}

// ---------------- combine split-KV x4 fp16 partials: ao = sum(po)/sum(l), bf16 out ----------------
__global__ __launch_bounds__(256) void k_comb(const unsigned short* __restrict__ po0,
                                              const unsigned short* __restrict__ po1,
                                              const unsigned short* __restrict__ po2,
                                              const unsigned short* __restrict__ po3,
                                              const float* __restrict__ lp,
                                              unsigned short* __restrict__ ao) {
    const int idx8 = blockIdx.x * 256 + threadIdx.x;   // 8 elems per thread
    const int e = idx8 * 8;
    const int row = e >> 10, c = e & 1023;
    const int h = c >> 6, b = row >> 11, s = row & 2047;
    const size_t li = ((size_t)(b * 16 + h) << 11) + s;
    const float lsum = lp[li] + lp[65536 + li] + lp[2 * 65536 + li] + lp[3 * 65536 + li];
    const float rinv = __builtin_amdgcn_rcpf(lsum);
    short8 a0 = ((const short8*)po0)[idx8];
    short8 a1 = ((const short8*)po1)[idx8];
    short8 a2 = ((const short8*)po2)[idx8];
    short8 a3 = ((const short8*)po3)[idx8];
    short8 o;
#pragma unroll
    for (int j = 0; j < 8; ++j) {
        float s4 = (h2f((unsigned short)a0[j]) + h2f((unsigned short)a1[j]))
                 + (h2f((unsigned short)a2[j]) + h2f((unsigned short)a3[j]));
        o[j] = (short)f2bf(s4 * rinv);
    }
    ((short8*)ao)[idx8] = o;
}

// ---------------- residual + LayerNorm: out = LN(x + oproj) ----------------
__global__ __launch_bounds__(256) void k_ln(const float* __restrict__ x, const unsigned short* __restrict__ op,
                                            const float* __restrict__ g, const float* __restrict__ be,
                                            float* __restrict__ out) {
    const int row = blockIdx.x, tid = threadIdx.x;
    const float4 xv = ((const float4*)(x + (size_t)row * 1024))[tid];
    const us4 ov = ((const us4*)(op + (size_t)row * 1024))[tid];
    float4 v = { xv.x + bf2f(ov.x), xv.y + bf2f(ov.y), xv.z + bf2f(ov.z), xv.w + bf2f(ov.w) };
    float sum = v.x + v.y + v.z + v.w;
    float ss = v.x * v.x + v.y * v.y + v.z * v.z + v.w * v.w;
#pragma unroll
    for (int xm = 1; xm < 64; xm <<= 1) {
        sum += __shfl_xor(sum, xm, 64);
        ss += __shfl_xor(ss, xm, 64);
    }
    __shared__ float red[8];
    const int lane = tid & 63, w = tid >> 6;
    if (lane == 0) { red[w] = sum; red[4 + w] = ss; }
    __syncthreads();
    sum = red[0] + red[1] + red[2] + red[3];
    ss = red[4] + red[5] + red[6] + red[7];
    const float mu = sum * (1.0f / 1024.0f);
    const float rstd = rsqrtf(ss * (1.0f / 1024.0f) - mu * mu + 1e-5f);
    const float4 gv = ((const float4*)g)[tid];
    const float4 bv = ((const float4*)be)[tid];
    float4 o = { (v.x - mu) * rstd * gv.x + bv.x, (v.y - mu) * rstd * gv.y + bv.y,
                 (v.z - mu) * rstd * gv.z + bv.z, (v.w - mu) * rstd * gv.w + bv.w };
    ((float4*)(out + (size_t)row * 1024))[tid] = o;
}

extern "C" void kernel_launch(void* const* d_in, const int* in_sizes, int n_in,
                              void* d_out, int out_size, void* d_ws, size_t ws_size,
                              hipStream_t stream) {
    const float* x        = (const float*)d_in[0];
    const int*   mask     = (const int*)d_in[1];
    const float* wq       = (const float*)d_in[2];
    const float* bq       = (const float*)d_in[3];
    const float* wk       = (const float*)d_in[4];
    const float* bk       = (const float*)d_in[5];
    const float* wv       = (const float*)d_in[6];
    const float* bv       = (const float*)d_in[7];
    const float* wo       = (const float*)d_in[8];
    const float* bo       = (const float*)d_in[9];
    const float* ln_g     = (const float*)d_in[11];
    const float* ln_b     = (const float*)d_in[12];

    char* ws = (char*)d_ws;
    unsigned short* xb  = (unsigned short*)(ws);                    // 0-8 MB   x bf16; reused as po0
    unsigned short* wt  = (unsigned short*)(ws + (8ll  << 20));     // 8-16 MB  4x Wt bf16
    unsigned short* qb  = (unsigned short*)(ws + (16ll << 20));     // 16-24 MB Q; reused as ao
    unsigned short* kb  = (unsigned short*)(ws + (24ll << 20));     // 24-32 MB K; reused as opj
    unsigned short* vtb = (unsigned short*)(ws + (32ll << 20));     // 32-40 MB V^T (mask-zeroed)
    unsigned short* po1 = (unsigned short*)(ws + (40ll << 20));     // 40-48 MB partial O half1 (fp16)
    float*          lp  = (float*)(ws + (48ll << 20));              // 1 MB: l partials [4][32][2048]
    unsigned short* po0 = xb;                                       // fp16
    unsigned short* po2 = (unsigned short*)d_out;                   // d_out as scratch (16 MB):
    unsigned short* po3 = po2 + (4ll << 20);                        // po2 + po3 fp16; k_ln overwrites later
    unsigned short* ao  = qb;
    unsigned short* opj = kb;

    const float qscale = 0.125f * 1.44269504f;   // 1/sqrt(Hd) * log2(e), folded into Q
    // attn_bias (1,H,1,1) is constant across keys => softmax shift-invariant => dropped.

    k_prep<<<8192, 256, 0, stream>>>(x, xb, wq, wk, wv, wo, wt);
    k_gemm_qkv<<<512, 256, 0, stream>>>(xb, wt, bq, bk, bv, mask, qb, kb, vtb, qscale);
    k_attn<<<2048, 256, 0, stream>>>(qb, kb, vtb, mask, po0, po1, po2, po3, lp);
    k_comb<<<2048, 256, 0, stream>>>(po0, po1, po2, po3, lp, ao);
    k_gemm_o<<<256, 256, 0, stream>>>(ao, wt + (3u << 20), bo, opj);
    k_ln<<<4096, 256, 0, stream>>>(x, opj, ln_g, ln_b, (float*)d_out);
}

// Round 16
// 123.563 us; speedup vs baseline: 1.4280x; 1.0465x over previous
//
#include <hip/hip_runtime.h>

typedef __attribute__((ext_vector_type(8))) short short8;
typedef __attribute__((ext_vector_type(4))) float f32x4;
typedef __attribute__((ext_vector_type(16))) float f32x16;
typedef __attribute__((ext_vector_type(4))) unsigned short us4;

#define DEV __device__ __forceinline__

#define GLD16(gp, lp) __builtin_amdgcn_global_load_lds( \
    (const __attribute__((address_space(1))) void*)(gp), \
    (__attribute__((address_space(3))) void*)(lp), 16, 0, 0)

DEV unsigned short f2bf(float f) {
    union { float f; unsigned u; } v; v.f = f;
    unsigned r = v.u + 0x7fffu + ((v.u >> 16) & 1u);
    return (unsigned short)(r >> 16);
}

DEV float bf2f(unsigned short u) {
    union { unsigned u; float f; } v; v.u = (unsigned)u << 16;
    return v.f;
}

DEV unsigned short f2h(float f) {
    union { _Float16 h; unsigned short u; } v; v.h = (_Float16)f; return v.u;
}

DEV float h2f(unsigned short u) {
    union { _Float16 h; unsigned short u; } v; v.u = u; return (float)v.h;
}

DEV unsigned cvtpk(float lo, float hi) {
    unsigned r;
    asm("v_cvt_pk_bf16_f32 %0, %1, %2" : "=v"(r) : "v"(lo), "v"(hi));
    return r;
}

DEV float fexp2(float x) {
#if __has_builtin(__builtin_amdgcn_exp2f)
    return __builtin_amdgcn_exp2f(x);
#else
    return __expf(x * 0.69314718056f);
#endif
}

// ---------------- prep: x->bf16 convert (blocks 0..4095) + W transpose (blocks 4096..8191) ----------------
__global__ __launch_bounds__(256) void k_prep(const float* __restrict__ x, unsigned short* __restrict__ xb,
                                              const float* __restrict__ wq, const float* __restrict__ wk,
                                              const float* __restrict__ wv, const float* __restrict__ wo,
                                              unsigned short* __restrict__ wt) {
    __shared__ float tile[32][33];
    const int id = blockIdx.x, tid = threadIdx.x;
    if (id < 4096) {
        int i = id * 256 + tid;
        float4 v = ((const float4*)x)[i];
        us4 o = { f2bf(v.x), f2bf(v.y), f2bf(v.z), f2bf(v.w) };
        ((us4*)xb)[i] = o;
        return;
    }
    const int t = (id - 4096) & 1023, z = (id - 4096) >> 10;
    const float* src = (z == 0) ? wq : (z == 1) ? wk : (z == 2) ? wv : wo;
    unsigned short* dst = wt + (size_t)z * (1u << 20);
    const int n0 = (t & 31) * 32, k0 = (t >> 5) * 32;
    const int tx = tid & 31, ty = tid >> 5;
#pragma unroll
    for (int i = 0; i < 4; ++i)
        tile[ty + i * 8][tx] = src[(size_t)(k0 + ty + i * 8) * 1024 + n0 + tx];
    __syncthreads();
#pragma unroll
    for (int i = 0; i < 4; ++i)
        dst[(size_t)(n0 + ty + i * 8) * 1024 + k0 + tx] = f2bf(tile[tx][ty + i * 8]);
}

// ---------------- fused QKV GEMM (bf16 A, reg-staged, XCD-swizzled grid) ----------------
__global__ __launch_bounds__(256) void k_gemm_qkv(const unsigned short* __restrict__ A,
                                                  const unsigned short* __restrict__ Wt,
                                                  const float* __restrict__ bq,
                                                  const float* __restrict__ bk,
                                                  const float* __restrict__ bv,
                                                  const int* __restrict__ mask,
                                                  unsigned short* __restrict__ Qo,
                                                  unsigned short* __restrict__ Ko,
                                                  unsigned short* __restrict__ Vo,
                                                  float qscale) {
    __shared__ unsigned short lA[2][128 * 32];
    __shared__ unsigned short lB[2][3][64 * 32];
    const int id = blockIdx.x;
    const int m0 = ((id & 7) * 4 + ((id >> 3) & 3)) * 128;
    const int n0 = (id >> 5) * 64;
    const int tid = threadIdx.x;
    const int lane = tid & 63;
    const int w = tid >> 6, wm = w >> 1, wn = w & 1;

    const int arow0 = tid >> 2, acl = tid & 3;
    const int arow1 = (tid + 256) >> 2;
    const int brow = tid >> 2;
    const unsigned short* agp0 = A + (size_t)(m0 + arow0) * 1024 + acl * 8;
    const unsigned short* agp1 = A + (size_t)(m0 + arow1) * 1024 + acl * 8;
    const unsigned short* bgp[3];
#pragma unroll
    for (int z = 0; z < 3; ++z)
        bgp[z] = Wt + ((size_t)z << 20) + (size_t)(n0 + brow) * 1024 + acl * 8;
    const int apc0 = ((arow0 << 2) | (acl ^ ((arow0 >> 1) & 3))) * 8;
    const int apc1 = ((arow1 << 2) | (acl ^ ((arow1 >> 1) & 3))) * 8;
    const int bpc  = ((brow  << 2) | (acl ^ ((brow  >> 1) & 3))) * 8;

    int ach[4], bch[2];
#pragma unroll
    for (int mt = 0; mt < 4; ++mt) {
        int row = wm * 64 + mt * 16 + (lane & 15);
        ach[mt] = ((row << 2) | ((lane >> 4) ^ ((row >> 1) & 3))) * 8;
    }
#pragma unroll
    for (int nt = 0; nt < 2; ++nt) {
        int row = wn * 32 + nt * 16 + (lane & 15);
        bch[nt] = ((row << 2) | ((lane >> 4) ^ ((row >> 1) & 3))) * 8;
    }

    f32x4 acc[3][4][2] = {};
    short8 ra0 = *(const short8*)agp0;
    short8 ra1 = *(const short8*)agp1;
    short8 rb[3];
#pragma unroll
    for (int z = 0; z < 3; ++z) rb[z] = *(const short8*)bgp[z];

    for (int t = 0; t < 32; ++t) {
        unsigned short* sA = lA[t & 1];
        *(short8*)(sA + apc0) = ra0;
        *(short8*)(sA + apc1) = ra1;
#pragma unroll
        for (int z = 0; z < 3; ++z)
            *(short8*)(lB[t & 1][z] + bpc) = rb[z];
        if (t < 31) {
            ra0 = *(const short8*)(agp0 + (t + 1) * 32);
            ra1 = *(const short8*)(agp1 + (t + 1) * 32);
#pragma unroll
            for (int z = 0; z < 3; ++z) rb[z] = *(const short8*)(bgp[z] + (t + 1) * 32);
        }
        __syncthreads();
        short8 af[4], bf[3][2];
#pragma unroll
        for (int mt = 0; mt < 4; ++mt) af[mt] = *(const short8*)(sA + ach[mt]);
#pragma unroll
        for (int z = 0; z < 3; ++z)
#pragma unroll
            for (int nt = 0; nt < 2; ++nt) bf[z][nt] = *(const short8*)(lB[t & 1][z] + bch[nt]);
#pragma unroll
        for (int z = 0; z < 3; ++z)
#pragma unroll
            for (int mt = 0; mt < 4; ++mt)
#pragma unroll
                for (int nt = 0; nt < 2; ++nt)
                    acc[z][mt][nt] = __builtin_amdgcn_mfma_f32_16x16x32_bf16(af[mt], bf[z][nt], acc[z][mt][nt], 0, 0, 0);
    }

#pragma unroll
    for (int z = 0; z < 3; ++z) {
        const float* bias = (z == 0) ? bq : (z == 1) ? bk : bv;
        const float scl = (z == 0) ? qscale : 1.0f;
        unsigned short* outp = (z == 0) ? Qo : (z == 1) ? Ko : Vo;
#pragma unroll
        for (int nt = 0; nt < 2; ++nt) {
            const int col = n0 + wn * 32 + nt * 16 + (lane & 15);
            const float bvv = bias[col];
            const int h = col >> 6, hd = col & 63;
#pragma unroll
            for (int mt = 0; mt < 4; ++mt) {
#pragma unroll
                for (int r = 0; r < 4; ++r) {
                    const int row = m0 + wm * 64 + mt * 16 + (lane >> 4) * 4 + r;
                    const int b = row >> 11, s = row & 2047;
                    float v = (acc[z][mt][nt][r] + bvv) * scl;
                    if (z == 2) {
                        v *= (mask[(size_t)b * 2048 + s] ? 1.0f : 0.0f);   // zero masked V rows
                        outp[(size_t)((b * 16 + h) * 64 + hd) * 2048 + s] = f2bf(v);
                    } else {
                        outp[(size_t)((b * 16 + h) * 2048 + s) * 64 + hd] = f2bf(v);
                    }
                }
            }
        }
    }
}

// ---------------- o-proj GEMM: 128x128 tile, 16 MFMA/step/wave, reg-staged, XCD-swizzled ----------------
__global__ __launch_bounds__(256) void k_gemm_o(const unsigned short* __restrict__ A,
                                                const unsigned short* __restrict__ Wt,
                                                const float* __restrict__ bias,
                                                unsigned short* __restrict__ out) {
    __shared__ unsigned short lA[2][128 * 32];
    __shared__ unsigned short lB[2][128 * 32];
    const int id = blockIdx.x;                       // 256 blocks: xcd=id&7, k=id>>3 (0..31)
    const int kk = id >> 3;
    const int m0 = ((id & 7) * 4 + (kk >> 3)) * 128;
    const int n0 = (kk & 7) * 128;
    const int tid = threadIdx.x;
    const int lane = tid & 63;
    const int w = tid >> 6, wm = w >> 1, wn = w & 1;

    const int arow0 = tid >> 2, acl = tid & 3;
    const int arow1 = arow0 + 64;
    const unsigned short* agp0 = A + (size_t)(m0 + arow0) * 1024 + acl * 8;
    const unsigned short* agp1 = A + (size_t)(m0 + arow1) * 1024 + acl * 8;
    const unsigned short* bgp0 = Wt + (size_t)(n0 + arow0) * 1024 + acl * 8;
    const unsigned short* bgp1 = Wt + (size_t)(n0 + arow1) * 1024 + acl * 8;
    const int apc0 = ((arow0 << 2) | (acl ^ ((arow0 >> 1) & 3))) * 8;
    const int apc1 = ((arow1 << 2) | (acl ^ ((arow1 >> 1) & 3))) * 8;

    int ach[4], bch[4];
#pragma unroll
    for (int mt = 0; mt < 4; ++mt) {
        int row = wm * 64 + mt * 16 + (lane & 15);
        ach[mt] = ((row << 2) | ((lane >> 4) ^ ((row >> 1) & 3))) * 8;
    }
#pragma unroll
    for (int nt = 0; nt < 4; ++nt) {
        int row = wn * 64 + nt * 16 + (lane & 15);
        bch[nt] = ((row << 2) | ((lane >> 4) ^ ((row >> 1) & 3))) * 8;
    }

    f32x4 acc[4][4] = {};
    short8 ra0 = *(const short8*)agp0;
    short8 ra1 = *(const short8*)agp1;
    short8 rb0 = *(const short8*)bgp0;
    short8 rb1 = *(const short8*)bgp1;

    for (int t = 0; t < 32; ++t) {
        unsigned short* sA = lA[t & 1];
        unsigned short* sB = lB[t & 1];
        *(short8*)(sA + apc0) = ra0;
        *(short8*)(sA + apc1) = ra1;
        *(short8*)(sB + apc0) = rb0;
        *(short8*)(sB + apc1) = rb1;
        if (t < 31) {
            ra0 = *(const short8*)(agp0 + (t + 1) * 32);
            ra1 = *(const short8*)(agp1 + (t + 1) * 32);
            rb0 = *(const short8*)(bgp0 + (t + 1) * 32);
            rb1 = *(const short8*)(bgp1 + (t + 1) * 32);
        }
        __syncthreads();
        short8 af[4], bf[4];
#pragma unroll
        for (int mt = 0; mt < 4; ++mt) af[mt] = *(const short8*)(sA + ach[mt]);
#pragma unroll
        for (int nt = 0; nt < 4; ++nt) bf[nt] = *(const short8*)(sB + bch[nt]);
#pragma unroll
        for (int mt = 0; mt < 4; ++mt)
#pragma unroll
            for (int nt = 0; nt < 4; ++nt)
                acc[mt][nt] = __builtin_amdgcn_mfma_f32_16x16x32_bf16(af[mt], bf[nt], acc[mt][nt], 0, 0, 0);
    }

#pragma unroll
    for (int nt = 0; nt < 4; ++nt) {
        const int col = n0 + wn * 64 + nt * 16 + (lane & 15);
        const float bv = bias[col];
#pragma unroll
        for (int mt = 0; mt < 4; ++mt)
#pragma unroll
            for (int r = 0; r < 4; ++r) {
                const int row = m0 + wm * 64 + mt * 16 + (lane >> 4) * 4 + r;
                out[(size_t)row * 1024 + col] = f2bf(acc[mt][nt][r] + bv);
            }
    }
}

// ---------------- flash attention: split-KV x2, 64 q-rows/wave, fp16 partials (R8-proven loop) ----------------
// 512 blocks (32bh x 8qt x 2half), (256,2): 2 blocks/CU. Per kt per wave:
// 8 K + 8 V + 4 m LDS b128 reads serve 64 q-rows (2 fragment groups share every read).
__global__ __launch_bounds__(256, 2) void k_attn(const unsigned short* __restrict__ Qb,
                                                 const unsigned short* __restrict__ Kb,
                                                 const unsigned short* __restrict__ Vt,
                                                 const int* __restrict__ mask,
                                                 unsigned short* __restrict__ po0,
                                                 unsigned short* __restrict__ po1,
                                                 float* __restrict__ lp) {   // lp[half][bh][s]
    __shared__ unsigned short ksm[2 * 4096];   // 16 KB, 2 buffers
    __shared__ unsigned short vsm[2 * 4096];   // 16 KB
    __shared__ unsigned short mv[1024];        // 2 KB: mask as bf16 {0,1} for this half
    const int id = blockIdx.x;
    const int xcd = id & 7, slot = id >> 3;                 // 512 blocks, slot 0..63
    const int half = slot & 1, qt = (slot >> 1) & 7, bh = xcd * 4 + (slot >> 4);
    const int b = bh >> 4, h = bh & 15;
    const int tid = threadIdx.x, l = tid & 63, w = tid >> 6;
    const int q = l & 31, hi = l >> 5;

    {
        int4 m = ((const int4*)(mask + b * 2048 + half * 1024))[tid];
        unsigned lo = (m.x ? 0x3F80u : 0u) | ((m.y ? 0x3F80u : 0u) << 16);
        unsigned hi2 = (m.z ? 0x3F80u : 0u) | ((m.w ? 0x3F80u : 0u) << 16);
        ((uint2*)mv)[tid] = make_uint2(lo, hi2);
    }
    asm volatile("s_waitcnt lgkmcnt(0)" ::: "memory");   // publish mv before first raw barrier

    const size_t bhS = (size_t)bh * 2048;
    const unsigned short* Kbh = Kb + (bhS + half * 1024) * 64;   // [1024 key][64 d]
    const unsigned short* Vbh = Vt + (size_t)bh * 64 * 2048;     // [64 d][2048 key]
    const int q0 = qt * 256 + w * 64;                            // wave owns 64 q-rows (2 groups)

    const int srow = l >> 3;
    const int sxor = 8 * ((l & 7) ^ ((l >> 3) & 7));
    const unsigned short* Ksrc = Kbh + (size_t)(w * 16 + srow) * 64 + sxor;
    const unsigned short* Vsrc = Vbh + (size_t)(w * 16 + srow) * 2048 + half * 1024 + sxor;
    unsigned short* lk0 = ksm + w * 1024;
    unsigned short* lv0 = vsm + w * 1024;

#define STAGE(kt_, buf_) { \
    const unsigned short* gk = Ksrc + (size_t)(kt_) * 4096; \
    const unsigned short* gv = Vsrc + (kt_) * 64; \
    unsigned short* lk = lk0 + (buf_) * 4096; \
    unsigned short* lv = lv0 + (buf_) * 4096; \
    GLD16(gk, lk); GLD16(gk + 512, lk + 512); \
    GLD16(gv, lv); GLD16(gv + 16384, lv + 512); }

    int kro[2][4], vro[2][2][2];
#pragma unroll
    for (int sub = 0; sub < 2; ++sub) {
#pragma unroll
        for (int db = 0; db < 4; ++db) {
            int key = q + sub * 32;
            kro[sub][db] = key * 128 + ((db * 32 + hi * 16) ^ ((key & 7) << 4));
        }
#pragma unroll
        for (int kg = 0; kg < 2; ++kg)
#pragma unroll
            for (int dh = 0; dh < 2; ++dh) {
                int row = q + dh * 32;
                vro[sub][kg][dh] = row * 128 + ((sub * 64 + kg * 32 + hi * 16) ^ ((row & 7) << 4));
            }
    }

    short8 qfA[4], qfB[4];
#pragma unroll
    for (int db = 0; db < 4; ++db) {
        qfA[db] = *(const short8*)(Qb + (bhS + q0 + q) * 64 + db * 16 + hi * 8);
        qfB[db] = *(const short8*)(Qb + (bhS + q0 + 32 + q) * 64 + db * 16 + hi * 8);
    }

    f32x16 o00 = {}, o01 = {}, o10 = {}, o11 = {}, ol0 = {}, ol1 = {};

    STAGE(0, 0);

    for (int kt = 0; kt < 16; ++kt) {
        const int cur = kt & 1;
        if (kt < 15) {
            STAGE(kt + 1, cur ^ 1);
            asm volatile("s_waitcnt vmcnt(4)" ::: "memory");
        } else {
            asm volatile("s_waitcnt vmcnt(0)" ::: "memory");
        }
        __builtin_amdgcn_s_barrier();
        __builtin_amdgcn_sched_barrier(0);
        const char* kb = (const char*)(ksm + cur * 4096);
        const char* vb = (const char*)(vsm + cur * 4096);
#pragma unroll
        for (int sub = 0; sub < 2; ++sub) {
            short8 kf0 = *(const short8*)(kb + kro[sub][0]);
            short8 kf1 = *(const short8*)(kb + kro[sub][1]);
            short8 kf2 = *(const short8*)(kb + kro[sub][2]);
            short8 kf3 = *(const short8*)(kb + kro[sub][3]);
            f32x16 sa0 = {}, sa1 = {};
            __builtin_amdgcn_s_setprio(1);
            sa0 = __builtin_amdgcn_mfma_f32_32x32x16_bf16(kf0, qfA[0], sa0, 0, 0, 0);
            sa1 = __builtin_amdgcn_mfma_f32_32x32x16_bf16(kf0, qfB[0], sa1, 0, 0, 0);
            sa0 = __builtin_amdgcn_mfma_f32_32x32x16_bf16(kf1, qfA[1], sa0, 0, 0, 0);
            sa1 = __builtin_amdgcn_mfma_f32_32x32x16_bf16(kf1, qfB[1], sa1, 0, 0, 0);
            sa0 = __builtin_amdgcn_mfma_f32_32x32x16_bf16(kf2, qfA[2], sa0, 0, 0, 0);
            sa1 = __builtin_amdgcn_mfma_f32_32x32x16_bf16(kf2, qfB[2], sa1, 0, 0, 0);
            sa0 = __builtin_amdgcn_mfma_f32_32x32x16_bf16(kf3, qfA[3], sa0, 0, 0, 0);
            sa1 = __builtin_amdgcn_mfma_f32_32x32x16_bf16(kf3, qfB[3], sa1, 0, 0, 0);
            __builtin_amdgcn_s_setprio(0);
            union { unsigned u[4]; short8 s8; } afA[2], afB[2];
            {
                float p[16];
#pragma unroll
                for (int r = 0; r < 16; ++r) p[r] = fexp2(sa0[r]);
#pragma unroll
                for (int kg = 0; kg < 2; ++kg) {
                    unsigned P0 = cvtpk(p[kg * 8 + 0], p[kg * 8 + 1]);
                    unsigned P1 = cvtpk(p[kg * 8 + 2], p[kg * 8 + 3]);
                    unsigned P2 = cvtpk(p[kg * 8 + 4], p[kg * 8 + 5]);
                    unsigned P3 = cvtpk(p[kg * 8 + 6], p[kg * 8 + 7]);
                    asm("v_permlane32_swap_b32 %0, %1" : "+v"(P0), "+v"(P2));
                    asm("v_permlane32_swap_b32 %0, %1" : "+v"(P1), "+v"(P3));
                    afA[kg].u[0] = P0; afA[kg].u[1] = P1; afA[kg].u[2] = P2; afA[kg].u[3] = P3;
                }
            }
            {
                float p[16];
#pragma unroll
                for (int r = 0; r < 16; ++r) p[r] = fexp2(sa1[r]);
#pragma unroll
                for (int kg = 0; kg < 2; ++kg) {
                    unsigned P0 = cvtpk(p[kg * 8 + 0], p[kg * 8 + 1]);
                    unsigned P1 = cvtpk(p[kg * 8 + 2], p[kg * 8 + 3]);
                    unsigned P2 = cvtpk(p[kg * 8 + 4], p[kg * 8 + 5]);
                    unsigned P3 = cvtpk(p[kg * 8 + 6], p[kg * 8 + 7]);
                    asm("v_permlane32_swap_b32 %0, %1" : "+v"(P0), "+v"(P2));
                    asm("v_permlane32_swap_b32 %0, %1" : "+v"(P1), "+v"(P3));
                    afB[kg].u[0] = P0; afB[kg].u[1] = P1; afB[kg].u[2] = P2; afB[kg].u[3] = P3;
                }
            }
#pragma unroll
            for (int kg = 0; kg < 2; ++kg) {
                short8 vf0 = *(const short8*)(vb + vro[sub][kg][0]);
                short8 vf1 = *(const short8*)(vb + vro[sub][kg][1]);
                short8 mfr = *(const short8*)(mv + kt * 64 + sub * 32 + kg * 16 + hi * 8);
                __builtin_amdgcn_s_setprio(1);
                o00 = __builtin_amdgcn_mfma_f32_32x32x16_bf16(afA[kg].s8, vf0, o00, 0, 0, 0);
                o01 = __builtin_amdgcn_mfma_f32_32x32x16_bf16(afA[kg].s8, vf1, o01, 0, 0, 0);
                o10 = __builtin_amdgcn_mfma_f32_32x32x16_bf16(afB[kg].s8, vf0, o10, 0, 0, 0);
                o11 = __builtin_amdgcn_mfma_f32_32x32x16_bf16(afB[kg].s8, vf1, o11, 0, 0, 0);
                ol0 = __builtin_amdgcn_mfma_f32_32x32x16_bf16(afA[kg].s8, mfr, ol0, 0, 0, 0);
                ol1 = __builtin_amdgcn_mfma_f32_32x32x16_bf16(afB[kg].s8, mfr, ol1, 0, 0, 0);
                __builtin_amdgcn_s_setprio(0);
            }
        }
        __builtin_amdgcn_sched_barrier(0);
        if (kt < 15) __builtin_amdgcn_s_barrier();
    }
#undef STAGE

    float* lpx = lp + (size_t)half * 65536 + bhS;
    if (q == 0) {
#pragma unroll
        for (int r = 0; r < 16; ++r) {
            int crow = (r & 3) + 8 * (r >> 2) + 4 * hi;
            lpx[q0 + crow] = ol0[r];
            lpx[q0 + 32 + crow] = ol1[r];
        }
    }
    unsigned short* popA = (half ? po1 : po0) + ((size_t)b * 2048 + q0) * 1024 + h * 64 + q;
    unsigned short* popB = popA + (size_t)32 * 1024;
#pragma unroll
    for (int r = 0; r < 16; ++r) {
        int qrow = (r & 3) + 8 * (r >> 2) + 4 * hi;
        popA[(size_t)qrow * 1024] = f2h(o00[r]);        // fp16 partials (2^-11 noise)
        popA[(size_t)qrow * 1024 + 32] = f2h(o01[r]);
        popB[(size_t)qrow * 1024] = f2h(o10[r]);
        popB[(size_t)qrow * 1024 + 32] = f2h(o11[r]);
    }
}

// ---------------- combine split-KV x2 fp16 partials: ao = (po0+po1)/(l0+l1), bf16 out ----------------
__global__ __launch_bounds__(256) void k_comb(const unsigned short* __restrict__ po0,
                                              const unsigned short* __restrict__ po1,
                                              const float* __restrict__ lp,
                                              unsigned short* __restrict__ ao) {
    const int idx8 = blockIdx.x * 256 + threadIdx.x;   // 8 elems per thread
    const int e = idx8 * 8;
    const int row = e >> 10, c = e & 1023;
    const int h = c >> 6, b = row >> 11, s = row & 2047;
    const size_t li = ((size_t)(b * 16 + h) << 11) + s;
    const float rinv = __builtin_amdgcn_rcpf(lp[li] + lp[65536 + li]);
    short8 a0 = ((const short8*)po0)[idx8];
    short8 a1 = ((const short8*)po1)[idx8];
    short8 o;
#pragma unroll
    for (int j = 0; j < 8; ++j) {
        float s2 = h2f((unsigned short)a0[j]) + h2f((unsigned short)a1[j]);
        o[j] = (short)f2bf(s2 * rinv);
    }
    ((short8*)ao)[idx8] = o;
}

// ---------------- residual + LayerNorm: out = LN(x + oproj) ----------------
__global__ __launch_bounds__(256) void k_ln(const float* __restrict__ x, const unsigned short* __restrict__ op,
                                            const float* __restrict__ g, const float* __restrict__ be,
                                            float* __restrict__ out) {
    const int row = blockIdx.x, tid = threadIdx.x;
    const float4 xv = ((const float4*)(x + (size_t)row * 1024))[tid];
    const us4 ov = ((const us4*)(op + (size_t)row * 1024))[tid];
    float4 v = { xv.x + bf2f(ov.x), xv.y + bf2f(ov.y), xv.z + bf2f(ov.z), xv.w + bf2f(ov.w) };
    float sum = v.x + v.y + v.z + v.w;
    float ss = v.x * v.x + v.y * v.y + v.z * v.z + v.w * v.w;
#pragma unroll
    for (int xm = 1; xm < 64; xm <<= 1) {
        sum += __shfl_xor(sum, xm, 64);
        ss += __shfl_xor(ss, xm, 64);
    }
    __shared__ float red[8];
    const int lane = tid & 63, w = tid >> 6;
    if (lane == 0) { red[w] = sum; red[4 + w] = ss; }
    __syncthreads();
    sum = red[0] + red[1] + red[2] + red[3];
    ss = red[4] + red[5] + red[6] + red[7];
    const float mu = sum * (1.0f / 1024.0f);
    const float rstd = rsqrtf(ss * (1.0f / 1024.0f) - mu * mu + 1e-5f);
    const float4 gv = ((const float4*)g)[tid];
    const float4 bv = ((const float4*)be)[tid];
    float4 o = { (v.x - mu) * rstd * gv.x + bv.x, (v.y - mu) * rstd * gv.y + bv.y,
                 (v.z - mu) * rstd * gv.z + bv.z, (v.w - mu) * rstd * gv.w + bv.w };
    ((float4*)(out + (size_t)row * 1024))[tid] = o;
}

extern "C" void kernel_launch(void* const* d_in, const int* in_sizes, int n_in,
                              void* d_out, int out_size, void* d_ws, size_t ws_size,
                              hipStream_t stream) {
    const float* x        = (const float*)d_in[0];
    const int*   mask     = (const int*)d_in[1];
    const float* wq       = (const float*)d_in[2];
    const float* bq       = (const float*)d_in[3];
    const float* wk       = (const float*)d_in[4];
    const float* bk       = (const float*)d_in[5];
    const float* wv       = (const float*)d_in[6];
    const float* bv       = (const float*)d_in[7];
    const float* wo       = (const float*)d_in[8];
    const float* bo       = (const float*)d_in[9];
    const float* ln_g     = (const float*)d_in[11];
    const float* ln_b     = (const float*)d_in[12];

    char* ws = (char*)d_ws;
    unsigned short* xb  = (unsigned short*)(ws);                    // 0-8 MB   x bf16; reused as po0
    unsigned short* wt  = (unsigned short*)(ws + (8ll  << 20));     // 8-16 MB  4x Wt bf16
    unsigned short* qb  = (unsigned short*)(ws + (16ll << 20));     // 16-24 MB Q; reused as ao
    unsigned short* kb  = (unsigned short*)(ws + (24ll << 20));     // 24-32 MB K; reused as opj
    unsigned short* vtb = (unsigned short*)(ws + (32ll << 20));     // 32-40 MB V^T (mask-zeroed)
    unsigned short* po1 = (unsigned short*)(ws + (40ll << 20));     // 40-48 MB partial O half1 (fp16)
    float*          lp  = (float*)(ws + (48ll << 20));              // 512 KB: l partials [2][32][2048]
    unsigned short* po0 = xb;                                       // fp16
    unsigned short* ao  = qb;
    unsigned short* opj = kb;

    const float qscale = 0.125f * 1.44269504f;   // 1/sqrt(Hd) * log2(e), folded into Q
    // attn_bias (1,H,1,1) is constant across keys => softmax shift-invariant => dropped.

    k_prep<<<8192, 256, 0, stream>>>(x, xb, wq, wk, wv, wo, wt);
    k_gemm_qkv<<<512, 256, 0, stream>>>(xb, wt, bq, bk, bv, mask, qb, kb, vtb, qscale);
    k_attn<<<512, 256, 0, stream>>>(qb, kb, vtb, mask, po0, po1, lp);
    k_comb<<<2048, 256, 0, stream>>>(po0, po1, lp, ao);
    k_gemm_o<<<256, 256, 0, stream>>>(ao, wt + (3u << 20), bo, opj);
    k_ln<<<4096, 256, 0, stream>>>(x, opj, ln_g, ln_b, (float*)d_out);
}